// Round 10
// baseline (822.310 us; speedup 1.0000x reference)
//
#include <hip/hip_runtime.h>
#include <hip/hip_bf16.h>
#include <cstdint>
#include <cstddef>

#define NN 4096
#define SINK_ITERS 20
#define EPSV 1e-6f

typedef unsigned short u16;
typedef __attribute__((ext_vector_type(8))) short bf16x8;
typedef __attribute__((ext_vector_type(4))) short bf16x4;
typedef __attribute__((ext_vector_type(4))) float f32x4;

__device__ __forceinline__ float bf2f(u16 u) {
  union { unsigned int i; float f; } x; x.i = ((unsigned int)u) << 16; return x.f;
}
__device__ __forceinline__ u16 f2bf(float f) {
  union { float f; unsigned int i; } x; x.f = f;
  unsigned int i = x.i;
  unsigned int r = i + 0x7FFFu + ((i >> 16) & 1u);   // round-to-nearest-even
  return (u16)(r >> 16);
}

typedef const __attribute__((address_space(1))) unsigned int* gas_p;
typedef __attribute__((address_space(3))) unsigned int* las_p;
__device__ __forceinline__ void gload16(const void* g, void* l) {
  __builtin_amdgcn_global_load_lds((gas_p)g, (las_p)l, 16, 0, 0);
}

// device-scope coherent accessors (L3 coherence point; no cache-wide fences)
__device__ __forceinline__ void gstore(float* p, float v) {
  __hip_atomic_store(p, v, __ATOMIC_RELAXED, __HIP_MEMORY_SCOPE_AGENT);
}
__device__ __forceinline__ float gloadc(const float* p) {
  return __hip_atomic_load(p, __ATOMIC_RELAXED, __HIP_MEMORY_SCOPE_AGENT);
}

// ================= persistent Sinkhorn (fence-free barriers) + tail matP =================
#define SINK_WGS 256
#define SINK_SMEM (131072 + 1024 + 1024 + 8192)

__device__ __forceinline__ void gsyncF(unsigned* grp, int me, unsigned goal) {
  __syncthreads();                      // all waves' data stores at L3
  int t = threadIdx.x;
  if (t < 64) {
    if (t == 0)
      __hip_atomic_store(grp + me, goal, __ATOMIC_RELAXED, __HIP_MEMORY_SCOPE_AGENT);
    unsigned v;
    long spin = 0;
    do {
      v = (t < 16) ? __hip_atomic_load(grp + t, __ATOMIC_RELAXED, __HIP_MEMORY_SCOPE_AGENT)
                   : goal;
    } while (__any(v < goal) && ++spin < 500000000L);
  }
  asm volatile("" ::: "memory");        // no compile-time hoisting of data loads
  __syncthreads();
}

__global__ __launch_bounds__(512) void k_sinkhorn(
    const float* __restrict__ W, u16* __restrict__ Pt,
    float* __restrict__ Spart, float* __restrict__ Tpart, unsigned* bar) {
  extern __shared__ char smem[];
  u16* Kt = (u16*)smem;                       // [256][256] bf16
  float* u_loc = (float*)(smem + 131072);     // [256]
  float* v_loc = u_loc + 256;                 // [256]
  float* red = v_loc + 256;                   // [8][256]

  int wg = blockIdx.x;
  int a = wg >> 4, b = wg & 15;
  int i0 = a * 256, j0 = b * 256;
  int t = threadIdx.x;
  int lane = t & 63, wv = t >> 6;
  int cg = t & 31;

  unsigned* colbar = bar + b * 16;            // 16 flags: wgs (*, b), member a
  unsigned* rowbar = bar + (16 + a) * 16;     // 16 flags: wgs (a, *), member b

  // ---- stage exp(W) tile into LDS ----
#pragma unroll
  for (int k = 0; k < 32; ++k) {
    int q = t + 512 * k;
    int il = q >> 6;
    int jc = (q & 63) << 2;
    f32x4 wvv = *(const f32x4*)(W + (size_t)(i0 + il) * NN + (j0 + jc));
    bf16x4 r;
#pragma unroll
    for (int c = 0; c < 4; ++c) r[c] = (short)f2bf(expf(wvv[c]));
    *(bf16x4*)(Kt + il * 256 + jc) = r;
  }
  if (t < 256) { u_loc[t] = 1.f; v_loc[t] = 1.f; }
  __syncthreads();

  for (int it = 0; it < SINK_ITERS; ++it) {
    int par = (it & 1) * 16;
    // ===== Phase A: u update (from prev T partials) + partial colsum =====
    if (t < 256 && it > 0) {
      int pb = ((it - 1) & 1) * 16;
      float Ts = 0.f;
#pragma unroll
      for (int p = 0; p < 16; ++p) Ts += gloadc(&Tpart[(pb + p) * NN + i0 + t]);
      float ul = u_loc[t];
      u_loc[t] = ul / (ul * Ts + EPSV);
    }
    __syncthreads();

    float acc[8] = {0.f, 0.f, 0.f, 0.f, 0.f, 0.f, 0.f, 0.f};
#pragma unroll
    for (int k = 0; k < 16; ++k) {
      int row = (t >> 5) + 16 * k;
      bf16x8 kv = *(const bf16x8*)(Kt + row * 256 + cg * 8);
      float ui = u_loc[row];
#pragma unroll
      for (int c = 0; c < 8; ++c) acc[c] += ui * bf2f((u16)kv[c]);
    }
#pragma unroll
    for (int c = 0; c < 8; ++c) acc[c] += __shfl_xor(acc[c], 32, 64);
    if (lane < 32) {
#pragma unroll
      for (int c = 0; c < 8; ++c) red[wv * 256 + cg * 8 + c] = acc[c];
    }
    __syncthreads();
    if (t < 256) {
      float s = 0.f;
#pragma unroll
      for (int w = 0; w < 8; ++w) s += red[w * 256 + t];
      gstore(&Spart[(par + a) * NN + j0 + t], s);
    }
    gsyncF(colbar, a, (unsigned)(it + 1));

    // ===== Phase B: v update (from S partials) + partial rowsum =====
    if (t < 256) {
      float Ss = 0.f;
#pragma unroll
      for (int p = 0; p < 16; ++p) Ss += gloadc(&Spart[(par + p) * NN + j0 + t]);
      float vo = v_loc[t];
      v_loc[t] = vo / (vo * Ss + EPSV);
    }
    __syncthreads();

    f32x4 va = *(const f32x4*)(v_loc + cg * 8);
    f32x4 vb2 = *(const f32x4*)(v_loc + cg * 8 + 4);
    float tr[16];
#pragma unroll
    for (int k = 0; k < 16; ++k) {
      int row = (t >> 5) + 16 * k;
      bf16x8 kv = *(const bf16x8*)(Kt + row * 256 + cg * 8);
      float s = 0.f;
#pragma unroll
      for (int c = 0; c < 4; ++c) s += bf2f((u16)kv[c]) * va[c];
#pragma unroll
      for (int c = 0; c < 4; ++c) s += bf2f((u16)kv[4 + c]) * vb2[c];
      tr[k] = s;
    }
#pragma unroll
    for (int k = 0; k < 16; ++k) {
#pragma unroll
      for (int d = 1; d <= 16; d <<= 1) tr[k] += __shfl_xor(tr[k], d, 64);
    }
    if (lane == 0 || lane == 32) {
#pragma unroll
      for (int k = 0; k < 16; ++k) red[(t >> 5) + 16 * k] = tr[k];
    }
    __syncthreads();
    if (t < 256) gstore(&Tpart[(par + b) * NN + i0 + t], red[t]);
    gsyncF(rowbar, b, (unsigned)(it + 1));
  }

  // ---- final u_20 into u_loc (v_20 already in v_loc) ----
  if (t < 256) {
    int pb = ((SINK_ITERS - 1) & 1) * 16;
    float Ts = 0.f;
#pragma unroll
    for (int p = 0; p < 16; ++p) Ts += gloadc(&Tpart[(pb + p) * NN + i0 + t]);
    float ul = u_loc[t];
    u_loc[t] = ul / (ul * Ts + EPSV);
  }
  __syncthreads();

  // ---- tail matP: Pt[j0+jl][i0 + 0..255] = bf16(u_i * K_ij * v_j) ----
  {
    int jl = t & 255, h = t >> 8;
    float vv = v_loc[jl];
    size_t prow = (size_t)(j0 + jl) * NN + i0;
#pragma unroll
    for (int g = 0; g < 16; ++g) {
      int gg = h * 16 + g;
      int il0 = gg * 8;
      bf16x8 r;
#pragma unroll
      for (int e = 0; e < 8; ++e)
        r[e] = (short)f2bf(u_loc[il0 + e] * bf2f(Kt[(il0 + e) * 256 + jl]) * vv);
      *(bf16x8*)(Pt + prow + gg * 8) = r;
    }
  }
}

// ================= standalone x -> bf16 (full occupancy) =================
__global__ void k_f2bf(const float* __restrict__ X, u16* __restrict__ Xb, long n8) {
  long stride = (long)gridDim.x * blockDim.x;
  for (long i = (long)blockIdx.x * blockDim.x + threadIdx.x; i < n8; i += stride) {
    long idx = i * 8;
    f32x4 a = *(const f32x4*)(X + idx);
    f32x4 b = *(const f32x4*)(X + idx + 4);
    bf16x8 r;
#pragma unroll
    for (int c = 0; c < 4; ++c) r[c] = (short)f2bf(a[c]);
#pragma unroll
    for (int c = 0; c < 4; ++c) r[4 + c] = (short)f2bf(b[c]);
    *(bf16x8*)(Xb + idx) = r;
  }
}

// ========== GEMM 256x256 / BK=64 / 8 waves: per-phase barrier interleave ==========
// Top-of-loop counted vmcnt(8) (tile t staged 2 iters earlier -> ~0 stall).
// Per tile: 4 phases {ds_read quadrant -> barrier -> lgkmcnt(0) -> setprio(1)
// 16 MFMA setprio(0) -> barrier}; STAGE(t+2) at the tail (only safe point with
// 2-buffer LDS: all waves drained lgkm before ph3's closing barrier); ph4 is
// register-only MFMA hiding the stage issue. No sched_barrier pins.
#define GBM 256
#define GBN 256
#define GBK 64
#define GNT (NN / GBK)
#define GEMM_SMEM 131072

__global__ __launch_bounds__(512, 2) void k_gemm256(const u16* __restrict__ A,
                                                    const u16* __restrict__ Bt,
                                                    float* __restrict__ C) {
  extern __shared__ __align__(1024) char gsm[];
  // layout: buf d (0/1) at d*65536: A-half0 16K | A-half1 16K | B-half0 16K | B-half1 16K

  int bid = blockIdx.x;              // 1024 blocks
  int xcd = bid & 7, sidx = bid >> 3;
  int bm = (xcd << 3) | (sidx >> 4); // 0..63 (M stripe per XCD)
  int bn = sidx & 15;                // 0..15
  size_t m0 = (size_t)bm * GBM, n0 = (size_t)bn * GBN;

  int tid = threadIdx.x;
  int lane = tid & 63, w = tid >> 6;
  int wm = w >> 2, wn = w & 3;       // 2 x 4 waves -> 128x64 per wave
  int l15 = lane & 15, kgb = (lane >> 4) * 16;
  int xk = kgb ^ (((l15 >> 3) & 1) << 5);   // swizzled 16B-group offset (const per lane)

  int aoff[8], boff[4];
#pragma unroll
  for (int m = 0; m < 8; ++m) aoff[m] = (m * 16 + l15) * 64 + xk;
#pragma unroll
  for (int n = 0; n < 4; ++n) boff[n] = ((wn & 1) * 64 + n * 16 + l15) * 64 + xk;

  // staging: linear LDS dest, inverse-swizzled global src (involution bit5^=bit9)
  int dst2[2], sA[2][2], sB[2][2];
#pragma unroll
  for (int i = 0; i < 2; ++i) {
    int d = (i * 512 + tid) * 16;
    int L = d ^ (((d >> 9) & 1) << 5);
    int ks = L >> 13, r = (L >> 6) & 127, cb = L & 63;
    int kelem = ks * 32 + (cb >> 1);
    dst2[i] = d;
#pragma unroll
    for (int h = 0; h < 2; ++h) {
      sA[h][i] = (int)((m0 + h * 128 + r) * NN) + kelem;
      sB[h][i] = (int)((n0 + h * 128 + r) * NN) + kelem;
    }
  }

  f32x4 acc[8][4];
#pragma unroll
  for (int m = 0; m < 8; ++m)
#pragma unroll
    for (int n = 0; n < 4; ++n) acc[m][n] = (f32x4){0.f, 0.f, 0.f, 0.f};

#define STAGE_ALL(CUR, K0)                                                        \
  {                                                                               \
    char* base_ = gsm + (CUR) * 65536;                                            \
    _Pragma("unroll") for (int h_ = 0; h_ < 2; ++h_)                              \
      _Pragma("unroll") for (int i_ = 0; i_ < 2; ++i_)                            \
        gload16(A + (size_t)(sA[h_][i_] + (K0)), base_ + h_ * 16384 + dst2[i_]);  \
    _Pragma("unroll") for (int h_ = 0; h_ < 2; ++h_)                              \
      _Pragma("unroll") for (int i_ = 0; i_ < 2; ++i_)                            \
        gload16(Bt + (size_t)(sB[h_][i_] + (K0)), base_ + 32768 + h_ * 16384 + dst2[i_]); \
  }

  // prologue: tiles 0 and 1 in flight (8 loads/thread each; 16 outstanding)
  STAGE_ALL(0, 0)
  STAGE_ALL(1, GBK)

  for (int t = 0; t < GNT; ++t) {
    int cur = t & 1;
    // ---- tile t landed (issued 2 iters ago); tile t+1's 8 stay in flight ----
    if (t < GNT - 1) {
      asm volatile("s_waitcnt vmcnt(8)" ::: "memory");
    } else {
      asm volatile("s_waitcnt vmcnt(0)" ::: "memory");
    }
    __builtin_amdgcn_s_barrier();

    const char* Ab = gsm + cur * 65536 + wm * 16384;
    const char* Bb = gsm + cur * 65536 + 32768 + (wn >> 1) * 16384;

    bf16x8 af[4][2], bfr[4][2];

    // ---- ph1: read A m0-3 + B n0-1 -> MFMA m0-3 x n0-1 ----
#pragma unroll
    for (int m = 0; m < 4; ++m)
#pragma unroll
      for (int ks = 0; ks < 2; ++ks) af[m][ks] = *(const bf16x8*)(Ab + ks * 8192 + aoff[m]);
#pragma unroll
    for (int n = 0; n < 2; ++n)
#pragma unroll
      for (int ks = 0; ks < 2; ++ks) bfr[n][ks] = *(const bf16x8*)(Bb + ks * 8192 + boff[n]);
    __builtin_amdgcn_s_barrier();
    asm volatile("s_waitcnt lgkmcnt(0)" ::: "memory");
    __builtin_amdgcn_s_setprio(1);
#pragma unroll
    for (int m = 0; m < 4; ++m)
#pragma unroll
      for (int n = 0; n < 2; ++n)
#pragma unroll
        for (int ks = 0; ks < 2; ++ks)
          acc[m][n] = __builtin_amdgcn_mfma_f32_16x16x32_bf16(af[m][ks], bfr[n][ks], acc[m][n], 0, 0, 0);
    __builtin_amdgcn_s_setprio(0);
    __builtin_amdgcn_s_barrier();

    // ---- ph2: read B n2-3 -> MFMA m0-3 x n2-3 ----
#pragma unroll
    for (int n = 2; n < 4; ++n)
#pragma unroll
      for (int ks = 0; ks < 2; ++ks) bfr[n][ks] = *(const bf16x8*)(Bb + ks * 8192 + boff[n]);
    __builtin_amdgcn_s_barrier();
    asm volatile("s_waitcnt lgkmcnt(0)" ::: "memory");
    __builtin_amdgcn_s_setprio(1);
#pragma unroll
    for (int m = 0; m < 4; ++m)
#pragma unroll
      for (int n = 2; n < 4; ++n)
#pragma unroll
        for (int ks = 0; ks < 2; ++ks)
          acc[m][n] = __builtin_amdgcn_mfma_f32_16x16x32_bf16(af[m][ks], bfr[n][ks], acc[m][n], 0, 0, 0);
    __builtin_amdgcn_s_setprio(0);
    __builtin_amdgcn_s_barrier();

    // ---- ph3: read A m4-7 (overwrite af) -> MFMA m4-7 x n2-3 ----
#pragma unroll
    for (int m = 0; m < 4; ++m)
#pragma unroll
      for (int ks = 0; ks < 2; ++ks) af[m][ks] = *(const bf16x8*)(Ab + ks * 8192 + aoff[m + 4]);
    __builtin_amdgcn_s_barrier();
    asm volatile("s_waitcnt lgkmcnt(0)" ::: "memory");
    __builtin_amdgcn_s_setprio(1);
#pragma unroll
    for (int m = 0; m < 4; ++m)
#pragma unroll
      for (int n = 2; n < 4; ++n)
#pragma unroll
        for (int ks = 0; ks < 2; ++ks)
          acc[4 + m][n] = __builtin_amdgcn_mfma_f32_16x16x32_bf16(af[m][ks], bfr[n][ks], acc[4 + m][n], 0, 0, 0);
    __builtin_amdgcn_s_setprio(0);
    __builtin_amdgcn_s_barrier();   // all waves' lgkm drained -> buf[cur] reads done

    // ---- ph4: STAGE tile t+2 into buf[cur]; register-only MFMA m4-7 x n0-1 ----
    if (t + 2 < GNT) STAGE_ALL(cur, (t + 2) * GBK)
    __builtin_amdgcn_s_setprio(1);
#pragma unroll
    for (int m = 0; m < 4; ++m)
#pragma unroll
      for (int n = 0; n < 2; ++n)
#pragma unroll
        for (int ks = 0; ks < 2; ++ks)
          acc[4 + m][n] = __builtin_amdgcn_mfma_f32_16x16x32_bf16(af[m][ks], bfr[n][ks], acc[4 + m][n], 0, 0, 0);
    __builtin_amdgcn_s_setprio(0);
  }
#undef STAGE_ALL

  // ---- epilogue ----
#pragma unroll
  for (int m = 0; m < 8; ++m) {
    size_t gr = m0 + (size_t)wm * 128 + m * 16 + (lane >> 4) * 4;
#pragma unroll
    for (int n = 0; n < 4; ++n) {
      size_t gc = n0 + (size_t)wn * 64 + n * 16 + l15;
#pragma unroll
      for (int i = 0; i < 4; ++i)
        C[(gr + i) * NN + gc] = acc[m][n][i];
    }
  }
}

// ---------------- legacy 128x128 GEMM (fallback if 128KB LDS attr fails) ----------------
#define BM 128
#define BN 128
#define BK 32
#define NT (NN / BK)

__global__ __launch_bounds__(256) void k_gemm(const u16* __restrict__ A,
                                              const u16* __restrict__ Bt,
                                              float* __restrict__ C) {
  __shared__ __align__(16) u16 lA[2][BM * BK];
  __shared__ __align__(16) u16 lB[2][BN * BK];

  int bid = blockIdx.x;
  int swz = (bid & 7) * 512 + (bid >> 3);
  int bm = swz >> 5, bn = swz & 31;

  int tid = threadIdx.x;
  int lane = tid & 63, w = tid >> 6;
  int wm = (w >> 1) * 64, wn = (w & 1) * 64;
  size_t m0 = (size_t)bm * BM, n0 = (size_t)bn * BN;

  f32x4 acc[4][4];
#pragma unroll
  for (int a = 0; a < 4; ++a)
#pragma unroll
    for (int b = 0; b < 4; ++b) acc[a][b] = (f32x4){0.f, 0.f, 0.f, 0.f};

  int srow = tid >> 2;
  int skc = (tid & 3) * 8;

  auto stage = [&](int buf, int t) {
    int k0 = t * BK;
#pragma unroll
    for (int it = 0; it < 2; ++it) {
      int row = it * 64 + srow;
      gload16(A + (m0 + row) * NN + k0 + skc, &lA[buf][row * BK + skc]);
      gload16(Bt + (n0 + row) * NN + k0 + skc, &lB[buf][row * BK + skc]);
    }
  };

  stage(0, 0);
  __syncthreads();

  int arow = wm + (lane & 15);
  int brow = wn + (lane & 15);
  int kc = (lane >> 4) * 8;

  for (int t = 0; t < NT; ++t) {
    int cur = t & 1;
    if (t < NT - 1) stage(cur ^ 1, t + 1);
    bf16x8 af[4], bfr[4];
#pragma unroll
    for (int f = 0; f < 4; ++f) {
      af[f] = *(const bf16x8*)&lA[cur][(arow + f * 16) * BK + kc];
      bfr[f] = *(const bf16x8*)&lB[cur][(brow + f * 16) * BK + kc];
    }
#pragma unroll
    for (int fm = 0; fm < 4; ++fm)
#pragma unroll
      for (int fn = 0; fn < 4; ++fn)
        acc[fm][fn] = __builtin_amdgcn_mfma_f32_16x16x32_bf16(af[fm], bfr[fn], acc[fm][fn], 0, 0, 0);
    __syncthreads();
  }

#pragma unroll
  for (int fm = 0; fm < 4; ++fm) {
    int r0 = wm + fm * 16 + (lane >> 4) * 4;
#pragma unroll
    for (int fn = 0; fn < 4; ++fn) {
      int c0 = wn + fn * 16 + (lane & 15);
#pragma unroll
      for (int i = 0; i < 4; ++i) {
        C[(m0 + r0 + i) * NN + n0 + c0] = acc[fm][fn][i];
      }
    }
  }
}

extern "C" void kernel_launch(void* const* d_in, const int* in_sizes, int n_in,
                              void* d_out, int out_size, void* d_ws, size_t ws_size,
                              hipStream_t stream) {
  const float* x = (const float*)d_in[0];   // [4,4096,4096] f32
  const float* W = (const float*)d_in[1];   // [4096,4096] f32
  float* out = (float*)d_out;               // [4,4096,4096] f32

  char* ws = (char*)d_ws;
  const size_t XB_OFF = 0;                      // 128 MB: x as bf16
  const size_t PT_OFF = 134217728;              // 32 MB: Pt (B^T for GEMM)
  const size_t SC_OFF = 167772160;              // coop scratch
  if (ws_size < SC_OFF + (66 * (size_t)NN) * sizeof(float)) return;

  u16* xb = (u16*)(ws + XB_OFF);
  u16* Ptb = (u16*)(ws + PT_OFF);

  float* Sp = (float*)(ws + SC_OFF);            // [2][16][4096]
  float* Tp = Sp + 32 * NN;                     // [2][16][4096]
  unsigned* bar = (unsigned*)(Tp + 32 * NN);    // [32][16] flags (64B/group)

  k_f2bf<<<2048, 256, 0, stream>>>(x, xb, (long)out_size / 8);

  // ---- Sinkhorn (persistent; 256 CUs, 141KB dynamic LDS) + tail matP ----
  bool coop = true;
  int dev = 0;
  hipDeviceProp_t prop;
  if (hipGetDevice(&dev) != hipSuccess) coop = false;
  else if (hipGetDeviceProperties(&prop, dev) != hipSuccess) coop = false;
  else if (prop.multiProcessorCount < SINK_WGS) coop = false;
  if (coop && hipFuncSetAttribute((const void*)k_sinkhorn,
                                  hipFuncAttributeMaxDynamicSharedMemorySize,
                                  SINK_SMEM) != hipSuccess)
    coop = false;
  if (!coop) return;  // MI355X always satisfies these checks

  hipMemsetAsync(bar, 0, 32 * 16 * sizeof(unsigned), stream);
  k_sinkhorn<<<SINK_WGS, 512, SINK_SMEM, stream>>>(W, Ptb, Sp, Tp, bar);

  // ---- GEMM: prefer 256^2 pipelined kernel, fallback to 128^2 ----
  bool big = (hipFuncSetAttribute((const void*)k_gemm256,
                                  hipFuncAttributeMaxDynamicSharedMemorySize,
                                  GEMM_SMEM) == hipSuccess);
  if (big) {
    k_gemm256<<<1024, 512, GEMM_SMEM, stream>>>(xb, Ptb, out);
    if (hipGetLastError() != hipSuccess) big = false;
  }
  if (!big) k_gemm<<<4096, 256, 0, stream>>>(xb, Ptb, out);
}

// Round 11
// 707.590 us; speedup vs baseline: 1.1621x; 1.1621x over previous
//
#include <hip/hip_runtime.h>
#include <hip/hip_bf16.h>
#include <cstdint>
#include <cstddef>

#define NN 4096
#define SINK_ITERS 20
#define EPSV 1e-6f

typedef unsigned short u16;
typedef __attribute__((ext_vector_type(8))) short bf16x8;
typedef __attribute__((ext_vector_type(4))) short bf16x4;
typedef __attribute__((ext_vector_type(4))) float f32x4;

__device__ __forceinline__ float bf2f(u16 u) {
  union { unsigned int i; float f; } x; x.i = ((unsigned int)u) << 16; return x.f;
}
__device__ __forceinline__ u16 f2bf(float f) {
  union { float f; unsigned int i; } x; x.f = f;
  unsigned int i = x.i;
  unsigned int r = i + 0x7FFFu + ((i >> 16) & 1u);   // round-to-nearest-even
  return (u16)(r >> 16);
}

typedef const __attribute__((address_space(1))) unsigned int* gas_p;
typedef __attribute__((address_space(3))) unsigned int* las_p;
__device__ __forceinline__ void gload16(const void* g, void* l) {
  __builtin_amdgcn_global_load_lds((gas_p)g, (las_p)l, 16, 0, 0);
}

// device-scope coherent accessors (L3 coherence point; no cache-wide fences)
__device__ __forceinline__ void gstore(float* p, float v) {
  __hip_atomic_store(p, v, __ATOMIC_RELAXED, __HIP_MEMORY_SCOPE_AGENT);
}
__device__ __forceinline__ float gloadc(const float* p) {
  return __hip_atomic_load(p, __ATOMIC_RELAXED, __HIP_MEMORY_SCOPE_AGENT);
}

// ================= persistent Sinkhorn (fence-free barriers) + tail matP =================
#define SINK_WGS 256
#define SINK_SMEM (131072 + 1024 + 1024 + 8192)

__device__ __forceinline__ void gsyncF(unsigned* grp, int me, unsigned goal) {
  __syncthreads();                      // all waves' data stores at L3
  int t = threadIdx.x;
  if (t < 64) {
    if (t == 0)
      __hip_atomic_store(grp + me, goal, __ATOMIC_RELAXED, __HIP_MEMORY_SCOPE_AGENT);
    unsigned v;
    long spin = 0;
    do {
      v = (t < 16) ? __hip_atomic_load(grp + t, __ATOMIC_RELAXED, __HIP_MEMORY_SCOPE_AGENT)
                   : goal;
    } while (__any(v < goal) && ++spin < 500000000L);
  }
  asm volatile("" ::: "memory");        // no compile-time hoisting of data loads
  __syncthreads();
}

__global__ __launch_bounds__(512) void k_sinkhorn(
    const float* __restrict__ W, u16* __restrict__ Pt,
    float* __restrict__ Spart, float* __restrict__ Tpart, unsigned* bar) {
  extern __shared__ char smem[];
  u16* Kt = (u16*)smem;                       // [256][256] bf16
  float* u_loc = (float*)(smem + 131072);     // [256]
  float* v_loc = u_loc + 256;                 // [256]
  float* red = v_loc + 256;                   // [8][256]

  int wg = blockIdx.x;
  int a = wg >> 4, b = wg & 15;
  int i0 = a * 256, j0 = b * 256;
  int t = threadIdx.x;
  int lane = t & 63, wv = t >> 6;
  int cg = t & 31;

  unsigned* colbar = bar + b * 16;            // 16 flags: wgs (*, b), member a
  unsigned* rowbar = bar + (16 + a) * 16;     // 16 flags: wgs (a, *), member b

  // ---- stage exp(W) tile into LDS ----
#pragma unroll
  for (int k = 0; k < 32; ++k) {
    int q = t + 512 * k;
    int il = q >> 6;
    int jc = (q & 63) << 2;
    f32x4 wvv = *(const f32x4*)(W + (size_t)(i0 + il) * NN + (j0 + jc));
    bf16x4 r;
#pragma unroll
    for (int c = 0; c < 4; ++c) r[c] = (short)f2bf(expf(wvv[c]));
    *(bf16x4*)(Kt + il * 256 + jc) = r;
  }
  if (t < 256) { u_loc[t] = 1.f; v_loc[t] = 1.f; }
  __syncthreads();

  for (int it = 0; it < SINK_ITERS; ++it) {
    int par = (it & 1) * 16;
    // ===== Phase A: u update (from prev T partials) + partial colsum =====
    if (t < 256 && it > 0) {
      int pb = ((it - 1) & 1) * 16;
      float Ts = 0.f;
#pragma unroll
      for (int p = 0; p < 16; ++p) Ts += gloadc(&Tpart[(pb + p) * NN + i0 + t]);
      float ul = u_loc[t];
      u_loc[t] = ul / (ul * Ts + EPSV);
    }
    __syncthreads();

    float acc[8] = {0.f, 0.f, 0.f, 0.f, 0.f, 0.f, 0.f, 0.f};
#pragma unroll
    for (int k = 0; k < 16; ++k) {
      int row = (t >> 5) + 16 * k;
      bf16x8 kv = *(const bf16x8*)(Kt + row * 256 + cg * 8);
      float ui = u_loc[row];
#pragma unroll
      for (int c = 0; c < 8; ++c) acc[c] += ui * bf2f((u16)kv[c]);
    }
#pragma unroll
    for (int c = 0; c < 8; ++c) acc[c] += __shfl_xor(acc[c], 32, 64);
    if (lane < 32) {
#pragma unroll
      for (int c = 0; c < 8; ++c) red[wv * 256 + cg * 8 + c] = acc[c];
    }
    __syncthreads();
    if (t < 256) {
      float s = 0.f;
#pragma unroll
      for (int w = 0; w < 8; ++w) s += red[w * 256 + t];
      gstore(&Spart[(par + a) * NN + j0 + t], s);
    }
    gsyncF(colbar, a, (unsigned)(it + 1));

    // ===== Phase B: v update (from S partials) + partial rowsum =====
    if (t < 256) {
      float Ss = 0.f;
#pragma unroll
      for (int p = 0; p < 16; ++p) Ss += gloadc(&Spart[(par + p) * NN + j0 + t]);
      float vo = v_loc[t];
      v_loc[t] = vo / (vo * Ss + EPSV);
    }
    __syncthreads();

    f32x4 va = *(const f32x4*)(v_loc + cg * 8);
    f32x4 vb2 = *(const f32x4*)(v_loc + cg * 8 + 4);
    float tr[16];
#pragma unroll
    for (int k = 0; k < 16; ++k) {
      int row = (t >> 5) + 16 * k;
      bf16x8 kv = *(const bf16x8*)(Kt + row * 256 + cg * 8);
      float s = 0.f;
#pragma unroll
      for (int c = 0; c < 4; ++c) s += bf2f((u16)kv[c]) * va[c];
#pragma unroll
      for (int c = 0; c < 4; ++c) s += bf2f((u16)kv[4 + c]) * vb2[c];
      tr[k] = s;
    }
#pragma unroll
    for (int k = 0; k < 16; ++k) {
#pragma unroll
      for (int d = 1; d <= 16; d <<= 1) tr[k] += __shfl_xor(tr[k], d, 64);
    }
    if (lane == 0 || lane == 32) {
#pragma unroll
      for (int k = 0; k < 16; ++k) red[(t >> 5) + 16 * k] = tr[k];
    }
    __syncthreads();
    if (t < 256) gstore(&Tpart[(par + b) * NN + i0 + t], red[t]);
    gsyncF(rowbar, b, (unsigned)(it + 1));
  }

  // ---- final u_20 into u_loc (v_20 already in v_loc) ----
  if (t < 256) {
    int pb = ((SINK_ITERS - 1) & 1) * 16;
    float Ts = 0.f;
#pragma unroll
    for (int p = 0; p < 16; ++p) Ts += gloadc(&Tpart[(pb + p) * NN + i0 + t]);
    float ul = u_loc[t];
    u_loc[t] = ul / (ul * Ts + EPSV);
  }
  __syncthreads();

  // ---- tail matP: Pt[j0+jl][i0 + 0..255] = bf16(u_i * K_ij * v_j) ----
  {
    int jl = t & 255, h = t >> 8;
    float vv = v_loc[jl];
    size_t prow = (size_t)(j0 + jl) * NN + i0;
#pragma unroll
    for (int g = 0; g < 16; ++g) {
      int gg = h * 16 + g;
      int il0 = gg * 8;
      bf16x8 r;
#pragma unroll
      for (int e = 0; e < 8; ++e)
        r[e] = (short)f2bf(u_loc[il0 + e] * bf2f(Kt[(il0 + e) * 256 + jl]) * vv);
      *(bf16x8*)(Pt + prow + gg * 8) = r;
    }
  }
}

// ================= standalone x -> bf16 (full occupancy) =================
__global__ void k_f2bf(const float* __restrict__ X, u16* __restrict__ Xb, long n8) {
  long stride = (long)gridDim.x * blockDim.x;
  for (long i = (long)blockIdx.x * blockDim.x + threadIdx.x; i < n8; i += stride) {
    long idx = i * 8;
    f32x4 a = *(const f32x4*)(X + idx);
    f32x4 b = *(const f32x4*)(X + idx + 4);
    bf16x8 r;
#pragma unroll
    for (int c = 0; c < 4; ++c) r[c] = (short)f2bf(a[c]);
#pragma unroll
    for (int c = 0; c < 4; ++c) r[4 + c] = (short)f2bf(b[c]);
    *(bf16x8*)(Xb + idx) = r;
  }
}

// ========== GEMM 256x256 / BK=64 / 8 waves: m201 8-phase per-phase staging ==========
// Iteration = 2 K-tiles (dbuf0, dbuf1), 8 phases. Each phase stages exactly ONE
// half-tile (2 gload_lds/thread). Stage slots follow the WAR windows:
//   ph1,2 -> dbuf1.A (K 2t+1)   [dbuf1.A last read ph7 of prev iter]
//   ph3,4 -> dbuf0.B (K 2t+2)   [dbuf0.B last read ph2]
//   ph5,6 -> dbuf0.A (K 2t+2)   [dbuf0.A last read ph3]
//   ph7,8 -> dbuf1.B (K 2t+3)   [dbuf1.B last read ph6]
// Counted vmcnt(4) once per K-tile at end of ph4/ph8 (12 outstanding, keep
// newest 4) BEFORE the closing barrier -> all waves' needed loads landed.
#define GBM 256
#define GBN 256
#define GBK 64
#define GNT (NN / GBK)
#define GNT2 (GNT / 2)
#define GEMM_SMEM 131072

__global__ __launch_bounds__(512, 2) void k_gemm256(const u16* __restrict__ A,
                                                    const u16* __restrict__ Bt,
                                                    float* __restrict__ C) {
  extern __shared__ __align__(1024) char gsm[];
  // dbuf d at d*65536: A-h0 16K | A-h1 16K | B-h0 16K | B-h1 16K

  int bid = blockIdx.x;              // 1024 blocks
  int xcd = bid & 7, sidx = bid >> 3;
  int bm = (xcd << 3) | (sidx >> 4); // M stripe per XCD
  int bn = sidx & 15;
  size_t m0 = (size_t)bm * GBM, n0 = (size_t)bn * GBN;

  int tid = threadIdx.x;
  int lane = tid & 63, w = tid >> 6;
  int wm = w >> 2, wn = w & 3;       // 2 x 4 waves -> 128x64 per wave
  int l15 = lane & 15, kgb = (lane >> 4) * 16;
  int xk = kgb ^ (((l15 >> 3) & 1) << 5);

  int aoff[8], boff[4];
#pragma unroll
  for (int m = 0; m < 8; ++m) aoff[m] = (m * 16 + l15) * 64 + xk;
#pragma unroll
  for (int n = 0; n < 4; ++n) boff[n] = ((wn & 1) * 64 + n * 16 + l15) * 64 + xk;

  // staging: linear LDS dest, inverse-swizzled global src (involution bit5^=bit9)
  int dst2[2], sA[2][2], sB[2][2];
#pragma unroll
  for (int i = 0; i < 2; ++i) {
    int d = (i * 512 + tid) * 16;
    int L = d ^ (((d >> 9) & 1) << 5);
    int ks = L >> 13, r = (L >> 6) & 127, cb = L & 63;
    int kelem = ks * 32 + (cb >> 1);
    dst2[i] = d;
#pragma unroll
    for (int h = 0; h < 2; ++h) {
      sA[h][i] = (int)((m0 + h * 128 + r) * NN) + kelem;
      sB[h][i] = (int)((n0 + h * 128 + r) * NN) + kelem;
    }
  }

  f32x4 acc[8][4];
#pragma unroll
  for (int m = 0; m < 8; ++m)
#pragma unroll
    for (int n = 0; n < 4; ++n) acc[m][n] = (f32x4){0.f, 0.f, 0.f, 0.f};

#define ST_A(D, H, KT)                                                       \
  { char* b_ = gsm + (D) * 65536 + (H) * 16384;                              \
    gload16(A + (size_t)(sA[H][0] + (KT) * GBK), b_ + dst2[0]);              \
    gload16(A + (size_t)(sA[H][1] + (KT) * GBK), b_ + dst2[1]); }
#define ST_B(D, H, KT)                                                       \
  { char* b_ = gsm + (D) * 65536 + 32768 + (H) * 16384;                      \
    gload16(Bt + (size_t)(sB[H][0] + (KT) * GBK), b_ + dst2[0]);             \
    gload16(Bt + (size_t)(sB[H][1] + (KT) * GBK), b_ + dst2[1]); }

#define RD_A(BASE, M0)                                                       \
  _Pragma("unroll") for (int m = 0; m < 4; ++m)                              \
  _Pragma("unroll") for (int ks = 0; ks < 2; ++ks)                           \
      af[m][ks] = *(const bf16x8*)((BASE) + ks * 8192 + aoff[(M0) + m]);
#define RD_B(BASE, N0)                                                       \
  _Pragma("unroll") for (int n = 0; n < 2; ++n)                              \
  _Pragma("unroll") for (int ks = 0; ks < 2; ++ks)                           \
      bfr[(N0) + n][ks] = *(const bf16x8*)((BASE) + ks * 8192 + boff[(N0) + n]);
#define MM(AM, AN)                                                           \
  __builtin_amdgcn_s_setprio(1);                                             \
  _Pragma("unroll") for (int m = 0; m < 4; ++m)                              \
  _Pragma("unroll") for (int n = 0; n < 2; ++n)                              \
  _Pragma("unroll") for (int ks = 0; ks < 2; ++ks)                           \
      acc[(AM) + m][(AN) + n] = __builtin_amdgcn_mfma_f32_16x16x32_bf16(     \
          af[m][ks], bfr[(AN) + n][ks], acc[(AM) + m][(AN) + n], 0, 0, 0);   \
  __builtin_amdgcn_s_setprio(0);
#define BAR __builtin_amdgcn_s_barrier()
#define LGKM0 asm volatile("s_waitcnt lgkmcnt(0)" ::: "memory")

  // prologue: K0 (8 loads, oldest), K1.B (4 loads)
  ST_A(0, 0, 0) ST_A(0, 1, 0) ST_B(0, 0, 0) ST_B(0, 1, 0)
  ST_B(1, 0, 1) ST_B(1, 1, 1)
  asm volatile("s_waitcnt vmcnt(4)" ::: "memory");   // K0 landed; K1.B in flight
  BAR;

  for (int t2 = 0; t2 < GNT2; ++t2) {
    bool pf = (t2 < GNT2 - 1);
    int k1 = 2 * t2 + 1, k2 = 2 * t2 + 2, k3 = 2 * t2 + 3;

    // ---------------- K-tile 2t (dbuf0): phases 1-4 ----------------
    {
      const char* Ab = gsm + wm * 16384;
      const char* Bb = gsm + 32768 + (wn >> 1) * 16384;
      bf16x8 af[4][2], bfr[4][2];

      // ph1: read A m0-3 + B n0-1; stage dbuf1.A-h0 (K 2t+1)
      RD_A(Ab, 0) RD_B(Bb, 0)
      ST_A(1, 0, k1)
      asm volatile("s_waitcnt lgkmcnt(8)" ::: "memory");
      BAR; LGKM0;
      MM(0, 0)
      BAR;

      // ph2: read B n2-3; stage dbuf1.A-h1
      RD_B(Bb, 2)
      ST_A(1, 1, k1)
      BAR; LGKM0;
      MM(0, 2)
      BAR;

      // ph3: read A m4-7; stage dbuf0.B-h0 (K 2t+2)
      RD_A(Ab, 4)
      if (pf) ST_B(0, 0, k2)
      BAR; LGKM0;
      MM(4, 2)
      BAR;

      // ph4: stage dbuf0.B-h1; reg-only MFMA; per-K-tile counted wait
      if (pf) ST_B(0, 1, k2)
      MM(4, 0)
      if (pf) { asm volatile("s_waitcnt vmcnt(4)" ::: "memory"); }
      else    { asm volatile("s_waitcnt vmcnt(0)" ::: "memory"); }
      BAR;   // all waves' dbuf1 (K 2t+1) loads landed
    }

    // ---------------- K-tile 2t+1 (dbuf1): phases 5-8 ----------------
    {
      const char* Ab = gsm + 65536 + wm * 16384;
      const char* Bb = gsm + 65536 + 32768 + (wn >> 1) * 16384;
      bf16x8 af[4][2], bfr[4][2];

      // ph5: read A m0-3 + B n0-1; stage dbuf0.A-h0 (K 2t+2)
      RD_A(Ab, 0) RD_B(Bb, 0)
      if (pf) ST_A(0, 0, k2)
      asm volatile("s_waitcnt lgkmcnt(8)" ::: "memory");
      BAR; LGKM0;
      MM(0, 0)
      BAR;

      // ph6: read B n2-3; stage dbuf0.A-h1
      RD_B(Bb, 2)
      if (pf) ST_A(0, 1, k2)
      BAR; LGKM0;
      MM(0, 2)
      BAR;

      // ph7: read A m4-7; stage dbuf1.B-h0 (K 2t+3)
      RD_A(Ab, 4)
      if (pf) ST_B(1, 0, k3)
      BAR; LGKM0;
      MM(4, 2)
      BAR;

      // ph8: stage dbuf1.B-h1; reg-only MFMA; per-K-tile counted wait
      if (pf) ST_B(1, 1, k3)
      MM(4, 0)
      if (pf) { asm volatile("s_waitcnt vmcnt(4)" ::: "memory"); }
      else    { asm volatile("s_waitcnt vmcnt(0)" ::: "memory"); }
      BAR;   // all waves' dbuf0 (K 2t+2) loads landed
    }
  }
#undef ST_A
#undef ST_B
#undef RD_A
#undef RD_B
#undef MM
#undef BAR
#undef LGKM0

  // ---- epilogue ----
#pragma unroll
  for (int m = 0; m < 8; ++m) {
    size_t gr = m0 + (size_t)wm * 128 + m * 16 + (lane >> 4) * 4;
#pragma unroll
    for (int n = 0; n < 4; ++n) {
      size_t gc = n0 + (size_t)wn * 64 + n * 16 + l15;
#pragma unroll
      for (int i = 0; i < 4; ++i)
        C[(gr + i) * NN + gc] = acc[m][n][i];
    }
  }
}

// ---------------- legacy 128x128 GEMM (fallback if 128KB LDS attr fails) ----------------
#define BM 128
#define BN 128
#define BK 32
#define NT (NN / BK)

__global__ __launch_bounds__(256) void k_gemm(const u16* __restrict__ A,
                                              const u16* __restrict__ Bt,
                                              float* __restrict__ C) {
  __shared__ __align__(16) u16 lA[2][BM * BK];
  __shared__ __align__(16) u16 lB[2][BN * BK];

  int bid = blockIdx.x;
  int swz = (bid & 7) * 512 + (bid >> 3);
  int bm = swz >> 5, bn = swz & 31;

  int tid = threadIdx.x;
  int lane = tid & 63, w = tid >> 6;
  int wm = (w >> 1) * 64, wn = (w & 1) * 64;
  size_t m0 = (size_t)bm * BM, n0 = (size_t)bn * BN;

  f32x4 acc[4][4];
#pragma unroll
  for (int a = 0; a < 4; ++a)
#pragma unroll
    for (int b = 0; b < 4; ++b) acc[a][b] = (f32x4){0.f, 0.f, 0.f, 0.f};

  int srow = tid >> 2;
  int skc = (tid & 3) * 8;

  auto stage = [&](int buf, int t) {
    int k0 = t * BK;
#pragma unroll
    for (int it = 0; it < 2; ++it) {
      int row = it * 64 + srow;
      gload16(A + (m0 + row) * NN + k0 + skc, &lA[buf][row * BK + skc]);
      gload16(Bt + (n0 + row) * NN + k0 + skc, &lB[buf][row * BK + skc]);
    }
  };

  stage(0, 0);
  __syncthreads();

  int arow = wm + (lane & 15);
  int brow = wn + (lane & 15);
  int kc = (lane >> 4) * 8;

  for (int t = 0; t < NT; ++t) {
    int cur = t & 1;
    if (t < NT - 1) stage(cur ^ 1, t + 1);
    bf16x8 af[4], bfr[4];
#pragma unroll
    for (int f = 0; f < 4; ++f) {
      af[f] = *(const bf16x8*)&lA[cur][(arow + f * 16) * BK + kc];
      bfr[f] = *(const bf16x8*)&lB[cur][(brow + f * 16) * BK + kc];
    }
#pragma unroll
    for (int fm = 0; fm < 4; ++fm)
#pragma unroll
      for (int fn = 0; fn < 4; ++fn)
        acc[fm][fn] = __builtin_amdgcn_mfma_f32_16x16x32_bf16(af[fm], bfr[fn], acc[fm][fn], 0, 0, 0);
    __syncthreads();
  }

#pragma unroll
  for (int fm = 0; fm < 4; ++fm) {
    int r0 = wm + fm * 16 + (lane >> 4) * 4;
#pragma unroll
    for (int fn = 0; fn < 4; ++fn) {
      int c0 = wn + fn * 16 + (lane & 15);
#pragma unroll
      for (int i = 0; i < 4; ++i) {
        C[(m0 + r0 + i) * NN + n0 + c0] = acc[fm][fn][i];
      }
    }
  }
}

extern "C" void kernel_launch(void* const* d_in, const int* in_sizes, int n_in,
                              void* d_out, int out_size, void* d_ws, size_t ws_size,
                              hipStream_t stream) {
  const float* x = (const float*)d_in[0];   // [4,4096,4096] f32
  const float* W = (const float*)d_in[1];   // [4096,4096] f32
  float* out = (float*)d_out;               // [4,4096,4096] f32

  char* ws = (char*)d_ws;
  const size_t XB_OFF = 0;                      // 128 MB: x as bf16
  const size_t PT_OFF = 134217728;              // 32 MB: Pt (B^T for GEMM)
  const size_t SC_OFF = 167772160;              // coop scratch
  if (ws_size < SC_OFF + (66 * (size_t)NN) * sizeof(float)) return;

  u16* xb = (u16*)(ws + XB_OFF);
  u16* Ptb = (u16*)(ws + PT_OFF);

  float* Sp = (float*)(ws + SC_OFF);            // [2][16][4096]
  float* Tp = Sp + 32 * NN;                     // [2][16][4096]
  unsigned* bar = (unsigned*)(Tp + 32 * NN);    // [32][16] flags (64B/group)

  k_f2bf<<<2048, 256, 0, stream>>>(x, xb, (long)out_size / 8);

  // ---- Sinkhorn (persistent; 256 CUs, 141KB dynamic LDS) + tail matP ----
  bool coop = true;
  int dev = 0;
  hipDeviceProp_t prop;
  if (hipGetDevice(&dev) != hipSuccess) coop = false;
  else if (hipGetDeviceProperties(&prop, dev) != hipSuccess) coop = false;
  else if (prop.multiProcessorCount < SINK_WGS) coop = false;
  if (coop && hipFuncSetAttribute((const void*)k_sinkhorn,
                                  hipFuncAttributeMaxDynamicSharedMemorySize,
                                  SINK_SMEM) != hipSuccess)
    coop = false;
  if (!coop) return;  // MI355X always satisfies these checks

  hipMemsetAsync(bar, 0, 32 * 16 * sizeof(unsigned), stream);
  k_sinkhorn<<<SINK_WGS, 512, SINK_SMEM, stream>>>(W, Ptb, Sp, Tp, bar);

  // ---- GEMM: prefer 256^2 8-phase kernel, fallback to 128^2 ----
  bool big = (hipFuncSetAttribute((const void*)k_gemm256,
                                  hipFuncAttributeMaxDynamicSharedMemorySize,
                                  GEMM_SMEM) == hipSuccess);
  if (big) {
    k_gemm256<<<1024, 512, GEMM_SMEM, stream>>>(xb, Ptb, out);
    if (hipGetLastError() != hipSuccess) big = false;
  }
  if (!big) k_gemm<<<4096, 256, 0, stream>>>(xb, Ptb, out);
}